// Round 5
// baseline (337.477 us; speedup 1.0000x reference)
//
#include <hip/hip_runtime.h>
#include <hip/hip_bf16.h>

#define N_NODES 100000
#define N_FEATS 512
#define HIDDEN 64
#define NUM_SAMPLES 5
#define NUM_CLASSES 16
#define BATCH 16384
#define N_TILES (N_NODES / 16)  // 6250 exactly

typedef __attribute__((ext_vector_type(8))) short bf16x8;
typedef __attribute__((ext_vector_type(8))) unsigned short u16x8;
typedef __attribute__((ext_vector_type(4))) float f32x4;

static __device__ __forceinline__ float bf2f(unsigned short s) {
    unsigned int u = ((unsigned int)s) << 16;
    return __builtin_bit_cast(float, u);
}
static __device__ __forceinline__ short f2bf(float v) {
    __hip_bfloat16 b = __float2bfloat16(v);
    return *reinterpret_cast<short*>(&b);
}
static __device__ __forceinline__ int clampi(int v) {
    return ((unsigned)v < (unsigned)N_NODES) ? v : 0;
}

// Kernel A v4: PQ[n][c] = feat @ [W1a|W1b]^T (bf16 out).
// 512 threads = 8 waves; wave w owns output col-block nb=w (16 cols).
//  - B-slice loaded DIRECTLY from w1f once per block (prep kernel eliminated):
//    bfrag[kk][lane*8+j] = bf16(w1[h][part*512 + kk*32 + quad*8 + j]),
//    h=(w*16+l16)&63, part=(w*16+l16)>>6  (same algebra the old prep used).
//  - A-tile [16][512] bf16 staged cooperatively in LDS (T2 XOR swizzle).
//  - C epilogue: acc staged to padded LDS cbuf[16][132] (66-dword row stride
//    -> the 4 quad-rows of each ds_write_b16 hit distinct banks), drained as
//    256 threads x 16B = 4KB fully-contiguous store per tile (replaces 2B
//    scattered stores). Drain rides the existing barrier-A: C-writes before
//    it, C-reads after it, next C-writes after barrier-B => race-free, no
//    extra barriers.
__global__ __launch_bounds__(512) void pq_gemm(const float* __restrict__ feat,
                                               const float* __restrict__ w1f,
                                               short* __restrict__ PQ) {
    __shared__ __align__(16) short at[16 * 512];   // 16 KB A-tile, swizzled
    __shared__ __align__(16) short cb[16 * 132];   // 4.1 KB C-tile, padded
    const int tid  = threadIdx.x;
    const int wave = tid >> 6;   // 0..7 == nb
    const int lane = tid & 63;
    const int quad = lane >> 4;
    const int l16  = lane & 15;
    const int tidr = tid >> 5;   // staging row 0..15
    const int tids = tid & 31;   // staging col-group 0..31

    // ---- B prologue: direct from w1f, convert once (64 VGPRs) ----
    bf16x8 bfrag[16];
    {
        const int cn = wave * 16 + l16;
        const int h = cn & 63, part = cn >> 6;
        const float* wb = w1f + h * 1024 + part * 512 + quad * 8;
#pragma unroll
        for (int kk = 0; kk < 16; kk++) {
            f32x4 lo = *reinterpret_cast<const f32x4*>(wb + kk * 32);
            f32x4 hi = *reinterpret_cast<const f32x4*>(wb + kk * 32 + 4);
#pragma unroll
            for (int j = 0; j < 4; j++) {
                bfrag[kk][j]     = f2bf(lo[j]);
                bfrag[kk][4 + j] = f2bf(hi[j]);
            }
        }
    }

    const int stride = gridDim.x;
    f32x4 ra[2][2];

#define LOAD_TILE(tt)                                                             \
    {                                                                             \
        const float* base = feat + (size_t)((tt) * 16 + tidr) * N_FEATS + tids * 8;\
        _Pragma("unroll")                                                         \
        for (int i = 0; i < 2; i++) {                                             \
            ra[i][0] = *reinterpret_cast<const f32x4*>(base + i * 256);           \
            ra[i][1] = *reinterpret_cast<const f32x4*>(base + i * 256 + 4);       \
        }                                                                         \
    }

    int t = blockIdx.x;
    if (t < N_TILES) LOAD_TILE(t)

    int have_c = 0, tprev = 0;
    for (; t < N_TILES; t += stride) {
        __syncthreads();  // barrier A: prev A reads done; prev C writes visible
        // drain previous tile's C (fully coalesced 4KB store)
        if (have_c && tid < 256) {
            const int row = tid >> 4, ch = tid & 15;
            bf16x8 v = *reinterpret_cast<const bf16x8*>(cb + row * 132 + ch * 8);
            *reinterpret_cast<bf16x8*>(
                PQ + (size_t)(tprev * 16 + row) * 128 + ch * 8) = v;
        }
        // stage A-tile from regs (convert once, b128 writes, T2 swizzle)
#pragma unroll
        for (int i = 0; i < 2; i++) {
            bf16x8 p;
#pragma unroll
            for (int j = 0; j < 4; j++) {
                p[j]     = f2bf(ra[i][0][j]);
                p[4 + j] = f2bf(ra[i][1][j]);
            }
            const int chunk = i * 32 + tids;           // 16B chunk in row
            const int cs = chunk ^ (tidr & 7);         // T2 swizzle
            *reinterpret_cast<bf16x8*>(at + tidr * 512 + cs * 8) = p;
        }
        // prefetch next tile (issued before the barrier; lands during MFMA)
        const int tn = t + stride;
        if (tn < N_TILES) LOAD_TILE(tn)
        __syncthreads();  // barrier B: A-tile ready

        f32x4 acc = (f32x4){0.f, 0.f, 0.f, 0.f};
#pragma unroll
        for (int kk = 0; kk < 16; kk++) {
            const int chunk = kk * 4 + quad;
            const int cs = chunk ^ (l16 & 7);
            bf16x8 afrag = *reinterpret_cast<const bf16x8*>(at + l16 * 512 + cs * 8);
            acc = __builtin_amdgcn_mfma_f32_16x16x32_bf16(afrag, bfrag[kk], acc, 0, 0, 0);
        }

        // stage C: row = quad*4+r, col = wave*16+l16 (padded stride 132)
#pragma unroll
        for (int r = 0; r < 4; r++)
            cb[(quad * 4 + r) * 132 + wave * 16 + l16] = f2bf(acc[r]);
        have_c = 1;
        tprev = t;
    }
    __syncthreads();
    if (have_c && tid < 256) {
        const int row = tid >> 4, ch = tid & 15;
        bf16x8 v = *reinterpret_cast<const bf16x8*>(cb + row * 132 + ch * 8);
        *reinterpret_cast<bf16x8*>(
            PQ + (size_t)(tprev * 16 + row) * 128 + ch * 8) = v;
    }
#undef LOAD_TILE
}

// Kernel B: h1[n][h] = relu(P[n][h] + 0.2*sum_s Q[neigh[n][s]][h]) -> H1[n][64]
// (reads PQ only, writes H1 only). 8 threads per node, 16B per thread.
__global__ __launch_bounds__(256) void h1_combine(const short* __restrict__ PQ,
                                                  const int* __restrict__ neigh_idx,
                                                  short* __restrict__ H1) {
    const int t = blockIdx.x * 256 + threadIdx.x;
    const int n = t >> 3;
    const int sub = t & 7;
    if (n >= N_NODES) return;

    u16x8 pv = *reinterpret_cast<const u16x8*>(PQ + (size_t)n * 128 + sub * 8);
    float s[8];
#pragma unroll
    for (int j = 0; j < 8; j++) s[j] = 0.f;
#pragma unroll
    for (int i = 0; i < NUM_SAMPLES; i++) {
        const int ni = clampi(neigh_idx[n * NUM_SAMPLES + i]);
        u16x8 qv = *reinterpret_cast<const u16x8*>(PQ + (size_t)ni * 128 + 64 + sub * 8);
#pragma unroll
        for (int j = 0; j < 8; j++) s[j] += bf2f(qv[j]);
    }
    u16x8 ov;
#pragma unroll
    for (int j = 0; j < 8; j++) {
        float v = bf2f(pv[j]) + 0.2f * s[j];
        v = v > 0.f ? v : 0.f;
        ov[j] = (unsigned short)f2bf(v);
    }
    *reinterpret_cast<u16x8*>(H1 + (size_t)n * 64 + sub * 8) = ov;
}

// Kernel C: 16 batch items per block (4 per wave). g = concat(h1[node],
// 0.2*sum_s h1[neigh[node][s]]); h2 = relu(g @ w2^T); out = h2 @ wcls^T (fp32).
// nodes-dtype (int64 vs int32) detected in-kernel via ballot (prep removed).
__global__ __launch_bounds__(256) void layer2_cls(const short* __restrict__ H1,
                                                  const int* __restrict__ nodes_i32,
                                                  const int* __restrict__ neigh_idx,
                                                  const float* __restrict__ w2,
                                                  const float* __restrict__ wcls,
                                                  float* __restrict__ out) {
    __shared__ float gbuf[16][128];
    __shared__ float h2buf[16][64];
    const int wave = threadIdx.x >> 6;
    const int lane = threadIdx.x & 63;
    const int b0 = blockIdx.x * 16;

    // int64 iff all odd int32 words (first 64) are zero
    const int odd = nodes_i32[2 * lane + 1];
    const int is64 = (__ballot(odd != 0) == 0ull) ? 1 : 0;

#pragma unroll
    for (int it = 0; it < 4; it++) {
        const int item = wave * 4 + it;
        const int b = b0 + item;
        const int node = clampi(nodes_i32[is64 ? 2 * b : b]);
        float selfv = bf2f((unsigned short)H1[(size_t)node * 64 + lane]);
        float ns = 0.f;
#pragma unroll
        for (int s = 0; s < NUM_SAMPLES; s++) {
            const int ni = clampi(neigh_idx[node * NUM_SAMPLES + s]);
            ns += bf2f((unsigned short)H1[(size_t)ni * 64 + lane]);
        }
        gbuf[item][lane] = selfv;
        gbuf[item][64 + lane] = 0.2f * ns;
    }
    __syncthreads();

    float acc[4] = {0.f, 0.f, 0.f, 0.f};
    const f32x4* w2r = reinterpret_cast<const f32x4*>(w2 + lane * 128);
#pragma unroll 8
    for (int k = 0; k < 32; k++) {
        f32x4 w = w2r[k];
#pragma unroll
        for (int it = 0; it < 4; it++) {
            f32x4 g = *reinterpret_cast<const f32x4*>(&gbuf[wave * 4 + it][k * 4]);
            acc[it] += g[0] * w[0] + g[1] * w[1] + g[2] * w[2] + g[3] * w[3];
        }
    }
#pragma unroll
    for (int it = 0; it < 4; it++) {
        float h2 = acc[it] > 0.f ? acc[it] : 0.f;
        h2buf[wave * 4 + it][lane] = h2;
    }
    __syncthreads();

    if (lane < NUM_CLASSES) {
        const f32x4* wcr = reinterpret_cast<const f32x4*>(wcls + lane * 64);
#pragma unroll
        for (int it = 0; it < 4; it++) {
            const int item = wave * 4 + it;
            const f32x4* hr = reinterpret_cast<const f32x4*>(&h2buf[item][0]);
            float o = 0.f;
#pragma unroll
            for (int k = 0; k < 16; k++) {
                f32x4 h = hr[k], w = wcr[k];
                o += h[0] * w[0] + h[1] * w[1] + h[2] * w[2] + h[3] * w[3];
            }
            out[(size_t)(b0 + item) * NUM_CLASSES + lane] = o;
        }
    }
}

extern "C" void kernel_launch(void* const* d_in, const int* in_sizes, int n_in,
                              void* d_out, int out_size, void* d_ws, size_t ws_size,
                              hipStream_t stream) {
    const float* feat = nullptr;      // 100000*512  = 51,200,000
    const float* w1 = nullptr;        // 64*1024     = 65,536
    const float* w2 = nullptr;        // 64*128      = 8,192
    const float* wcls = nullptr;      // 16*64       = 1,024
    const int* nodes = nullptr;       // 16,384
    const int* neigh_idx = nullptr;   // 100000*5    = 500,000
    for (int i = 0; i < n_in; i++) {
        switch (in_sizes[i]) {
            case 51200000: feat = (const float*)d_in[i]; break;
            case 65536:    w1 = (const float*)d_in[i]; break;
            case 8192:     w2 = (const float*)d_in[i]; break;
            case 1024:     wcls = (const float*)d_in[i]; break;
            case 16384:    nodes = (const int*)d_in[i]; break;
            case 500000:   neigh_idx = (const int*)d_in[i]; break;
            default: break;
        }
    }
    float* out = (float*)d_out;  // [16384,16] fp32

    // ws layout: [256..) legacy w1p region (unused); PQ bf16 [100000][128]
    // (25.6 MB); H1 bf16 [100000][64] (12.8 MB). Offsets kept stable.
    short* PQ  = (short*)((char*)d_ws + 256 + 131072);
    short* H1  = (short*)((char*)d_ws + 256 + 131072 + (size_t)N_NODES * 128 * 2);

    pq_gemm<<<512, 512, 0, stream>>>(feat, w1, PQ);
    h1_combine<<<(N_NODES * 8 + 255) / 256, 256, 0, stream>>>(PQ, neigh_idx, H1);
    layer2_cls<<<BATCH / 16, 256, 0, stream>>>(H1, nodes, neigh_idx, w2, wcls, out);
}